// Round 5
// baseline (38.441 us; speedup 1.0000x reference)
//
#include <hip/hip_runtime.h>

// Problem dims (fixed by the reference)
constexpr int cB = 32, cT = 15, cV = 100, cD = 768, cN = 160, cAP = 7;
constexpr int cD4 = cD / 4;         // 192 float4 per row
constexpr int cTV = cT * cV;        // 1500 candidate entries per batch
constexpr float cLN_EPS = 1e-12f;

// One block (384 threads = 2 groups x 192) per output row (b,n).
// Group g sums half of the gather rows; group 0 also does pos-GEMV + LN.
__global__ __launch_bounds__(384) void k_all(
    const float4* __restrict__ emb,      // [B*T*V, D/4]
    const float*  __restrict__ pos_fts,  // [B,N,7]
    const float4* __restrict__ step_tab, // [100, D/4]
    const float4* __restrict__ pos_w,    // [7, D/4]
    const float4* __restrict__ pos_b,    // [D/4]
    const float4* __restrict__ ln_g,     // [D/4]
    const float4* __restrict__ ln_b,     // [D/4]
    const int*    __restrict__ vp_lens,  // [B,T]
    const int*    __restrict__ vpids,    // [B,T]
    const int*    __restrict__ cand_ids, // [B,T,V]
    const int*    __restrict__ step_ids, // [B,N]
    float4*       __restrict__ out)      // [B*N, D/4]
{
    const int n   = blockIdx.x;          // node id 0..159
    const int b   = blockIdx.y;          // batch 0..31
    const int row = b * cN + n;
    const int tid = threadIdx.x;         // 0..383
    const int grp  = (tid >= 192) ? 1 : 0;
    const int slot = tid - (grp ? 192 : 0);   // float4 slot 0..191

    __shared__ float  sf[cAP];
    __shared__ int    slen[cT], svp[cT];
    __shared__ float  red[8];
    __shared__ int    scount;
    __shared__ int    slist[cTV];        // contributor entries (t*V+v), 6 KB
    __shared__ float4 spart[192];        // group-1 partial sums, 3 KB

    if (tid < cAP) sf[tid] = pos_fts[row * cAP + tid];
    if (tid >= 32 && tid < 32 + cT) slen[tid - 32] = vp_lens[b * cT + (tid - 32)];
    if (tid >= 64 && tid < 64 + cT) svp[tid - 64]  = vpids[b * cT + (tid - 64)];
    if (tid == 0) scount = 0;
    __syncthreads();

    // which step visited this node (if any)
    int tvis = -1;
#pragma unroll
    for (int k = cT - 1; k >= 0; --k) if (tvis < 0 && svp[k] == n) tvis = k;

    // candidate blocks: scan this batch's 1500 cand ids (int4) + LDS compact
    const bool isCand = (n > 0) && (tvis < 0);
    if (isCand && tid < cTV / 4) {       // 375 threads cover 1500 entries
        const int4 c4 = ((const int4*)(cand_ids + (size_t)b * cTV))[tid];
        const int e0 = tid * 4;
        const int cc[4] = {c4.x, c4.y, c4.z, c4.w};
#pragma unroll
        for (int k = 0; k < 4; ++k) {
            const int e = e0 + k;
            const int t = e / cV;
            const int v = e - t * cV;
            if (cc[k] == n && v < slen[t]) slist[atomicAdd(&scount, 1)] = e;
        }
    }
    __syncthreads();

    // pos GEMV (group 0 only) — overlaps group 1's gather loads
    float4 x = make_float4(0.f, 0.f, 0.f, 0.f);
    if (!grp) {
        x = pos_b[slot];
#pragma unroll
        for (int k = 0; k < cAP; ++k) {
            const float4 w = pos_w[k * cD4 + slot];
            const float f = sf[k];
            x.x = fmaf(f, w.x, x.x); x.y = fmaf(f, w.y, x.y);
            x.z = fmaf(f, w.z, x.z); x.w = fmaf(f, w.w, x.w);
        }
    }

    // ---- gather image feature (both groups, half the rows each) ----
    float ax = 0.f, ay = 0.f, az = 0.f, aw = 0.f;
    float wgt = 0.f;
    if (n > 0) {
        if (tvis >= 0) {
            // visited node: mean over valid views of step tvis
            const int len  = slen[tvis];
            const int half = (len + 1) >> 1;
            const int i0 = grp ? half : 0;
            const int i1 = grp ? len  : half;
            const float4* base = emb + (size_t)(b * cT + tvis) * cV * cD4 + slot;
            for (int i = i0; i < i1; i += 8) {
#pragma unroll
                for (int k = 0; k < 8; ++k) {
                    const int ik = min(i + k, i1 - 1);        // clamped, no OOB
                    const float4 a0 = base[(size_t)ik * cD4];
                    const float mk = (i + k < i1) ? 1.f : 0.f;
                    ax = fmaf(a0.x, mk, ax); ay = fmaf(a0.y, mk, ay);
                    az = fmaf(a0.z, mk, az); aw = fmaf(a0.w, mk, aw);
                }
            }
            wgt = 1.0f / (float)len;
        } else {
            // candidate node: mean over compacted contributor list
            const int m = scount;
            if (m > 0) {
                const int half = (m + 1) >> 1;
                const int j0 = grp ? half : 0;
                const int j1 = grp ? m    : half;
                const float4* base = emb + (size_t)b * cTV * cD4 + slot;
                for (int j = j0; j < j1; j += 8) {
#pragma unroll
                    for (int k = 0; k < 8; ++k) {
                        const int jk = min(j + k, j1 - 1);
                        const float4 a0 = base[(size_t)slist[jk] * cD4];
                        const float mk = (j + k < j1) ? 1.f : 0.f;
                        ax = fmaf(a0.x, mk, ax); ay = fmaf(a0.y, mk, ay);
                        az = fmaf(a0.z, mk, az); aw = fmaf(a0.w, mk, aw);
                    }
                }
                wgt = 1.0f / (float)m;
            }
        }
    }

    // group 1 publishes its partial
    if (grp) spart[slot] = make_float4(ax, ay, az, aw);

    // LN reduction (group 0's 3 waves)
    float s = 0.f, ss = 0.f;
    if (!grp) {
        s  = x.x + x.y + x.z + x.w;
        ss = x.x * x.x + x.y * x.y + x.z * x.z + x.w * x.w;
        for (int off = 32; off; off >>= 1) {
            s  += __shfl_down(s,  off, 64);
            ss += __shfl_down(ss, off, 64);
        }
        if ((tid & 63) == 0) { red[(tid >> 6) * 2] = s; red[(tid >> 6) * 2 + 1] = ss; }
    }
    __syncthreads();
    if (tid == 0) {
        const float S  = red[0] + red[2] + red[4];
        const float SS = red[1] + red[3] + red[5];
        const float mu  = S / (float)cD;
        const float var = SS / (float)cD - mu * mu;
        red[6] = mu;
        red[7] = rsqrtf(fmaxf(var, 0.f) + cLN_EPS);
    }
    __syncthreads();

    if (!grp) {
        const float mu = red[6], rs = red[7];
        const float4 p = spart[slot];
        ax += p.x; ay += p.y; az += p.z; aw += p.w;
        const int sid = step_ids[row];
        const float4 se = step_tab[(size_t)sid * cD4 + slot];
        const float4 g  = ln_g[slot];
        const float4 bb = ln_b[slot];
        float4 o;
        o.x = (x.x - mu) * rs * g.x + bb.x + se.x + ax * wgt;
        o.y = (x.y - mu) * rs * g.y + bb.y + se.y + ay * wgt;
        o.z = (x.z - mu) * rs * g.z + bb.z + se.z + az * wgt;
        o.w = (x.w - mu) * rs * g.w + bb.w + se.w + aw * wgt;
        out[(size_t)row * cD4 + slot] = o;
    }
}

// ---------------------------------------------------------------------------
extern "C" void kernel_launch(void* const* d_in, const int* in_sizes, int n_in,
                              void* d_out, int out_size, void* d_ws, size_t ws_size,
                              hipStream_t stream) {
    const float* emb      = (const float*)d_in[0];   // [B,T,V,D]
    const float* pos_fts  = (const float*)d_in[1];   // [B,N,7]
    const float* step_tab = (const float*)d_in[2];   // [100,D]
    const float* pos_w    = (const float*)d_in[3];   // [7,D]
    const float* pos_b    = (const float*)d_in[4];   // [D]
    const float* ln_g     = (const float*)d_in[5];   // [D]
    const float* ln_b     = (const float*)d_in[6];   // [D]
    const int*   vp_lens  = (const int*)d_in[7];     // [B,T]
    const int*   vpids    = (const int*)d_in[8];     // [B,T]
    const int*   cand     = (const int*)d_in[9];     // [B,T,V]
    const int*   step_ids = (const int*)d_in[10];    // [B,N]
    // d_in[11] = gmap_lens — unused by the reference output

    dim3 grid(cN, cB);
    k_all<<<grid, 384, 0, stream>>>((const float4*)emb, pos_fts,
                                    (const float4*)step_tab,
                                    (const float4*)pos_w, (const float4*)pos_b,
                                    (const float4*)ln_g, (const float4*)ln_b,
                                    vp_lens, vpids, cand, step_ids,
                                    (float4*)d_out);
}

// Round 6
// 31.858 us; speedup vs baseline: 1.2066x; 1.2066x over previous
//
#include <hip/hip_runtime.h>

// Problem dims (fixed by the reference)
constexpr int cB = 32, cT = 15, cV = 100, cD = 768, cN = 160, cAP = 7;
constexpr int cD4 = cD / 4;         // 192 float4 per row
constexpr int cTV = cT * cV;        // 1500 candidate entries per batch
constexpr int cXB = 3 * cT;         // 45 helper blocks per batch (quarters 1..3)
constexpr float cLN_EPS = 1e-12f;

// ---------------------------------------------------------------------------
// K1: grid (cN + 45, cB) x 192.
//   nb <  cN : output-row block (pos GEMV + LN + step emb + gather).
//              Visited rows sum only quarter 0 of their step's views.
//   nb >= cN : helper block -> partial sum of quarter q (1..3) of step t,
//              written to ws[(b*cT+t)*3 + (q-1)] (one writer, no atomics).
__global__ __launch_bounds__(192) void k_main(
    const float4* __restrict__ emb,      // [B*T*V, D/4]
    const float*  __restrict__ pos_fts,  // [B,N,7]
    const float4* __restrict__ step_tab, // [100, D/4]
    const float4* __restrict__ pos_w,    // [7, D/4]
    const float4* __restrict__ pos_b,    // [D/4]
    const float4* __restrict__ ln_g,     // [D/4]
    const float4* __restrict__ ln_b,     // [D/4]
    const int*    __restrict__ vp_lens,  // [B,T]
    const int*    __restrict__ vpids,    // [B,T]
    const int*    __restrict__ cand_ids, // [B,T,V]
    const int*    __restrict__ step_ids, // [B,N]
    float4*       __restrict__ wsv,      // [B*T*3, D/4] partial sums
    float4*       __restrict__ out)      // [B*N, D/4]
{
    const int nb  = blockIdx.x;          // 0..cN+44
    const int b   = blockIdx.y;          // 0..31
    const int tid = threadIdx.x;         // 0..191, owns float4 slot tid

    __shared__ float sf[cAP];
    __shared__ int   slen[cT], svp[cT];
    __shared__ float red[8];
    __shared__ int   scount;
    __shared__ int   slist[cTV];         // contributor entries (t*V+v), 6 KB

    if (tid < cT) slen[tid] = vp_lens[b * cT + tid];
    if (tid >= 32 && tid < 32 + cT) svp[tid - 32] = vpids[b * cT + (tid - 32)];

    // ---------------- helper blocks: one quarter of one step ----------------
    if (nb >= cN) {
        __syncthreads();
        const int j = nb - cN;           // 0..44
        const int t = j / 3;
        const int q = j - t * 3 + 1;     // quarter 1..3
        const int len = slen[t];
        const int lo = (len * q) >> 2;
        const int hi = (len * (q + 1)) >> 2;
        float ax = 0.f, ay = 0.f, az = 0.f, aw = 0.f;
        const float4* base = emb + (size_t)(b * cT + t) * cV * cD4 + tid;
        int i = lo;
        for (; i + 4 <= hi; i += 4) {
            const float4 a0 = base[(size_t)(i + 0) * cD4];
            const float4 a1 = base[(size_t)(i + 1) * cD4];
            const float4 a2 = base[(size_t)(i + 2) * cD4];
            const float4 a3 = base[(size_t)(i + 3) * cD4];
            ax += (a0.x + a1.x) + (a2.x + a3.x);
            ay += (a0.y + a1.y) + (a2.y + a3.y);
            az += (a0.z + a1.z) + (a2.z + a3.z);
            aw += (a0.w + a1.w) + (a2.w + a3.w);
        }
        for (; i < hi; ++i) {
            const float4 a0 = base[(size_t)i * cD4];
            ax += a0.x; ay += a0.y; az += a0.z; aw += a0.w;
        }
        wsv[(size_t)((b * cT + t) * 3 + (q - 1)) * cD4 + tid] =
            make_float4(ax, ay, az, aw);
        return;
    }

    // ---------------- output-row blocks ----------------
    const int n   = nb;
    const int row = b * cN + n;
    if (tid >= 64 && tid < 64 + cAP) sf[tid - 64] = pos_fts[row * cAP + (tid - 64)];
    if (tid == 0) scount = 0;
    __syncthreads();

    // which step visited this node (if any)
    int tvis = -1;
#pragma unroll
    for (int k = cT - 1; k >= 0; --k) if (tvis < 0 && svp[k] == n) tvis = k;

    // candidate blocks: scan this batch's 1500 cand ids (int4) + LDS compact
    const bool isCand = (n > 0) && (tvis < 0);
    if (isCand) {
        const int4* cb4 = (const int4*)(cand_ids + (size_t)b * cTV);
        for (int u = tid; u < cTV / 4; u += 192) {
            const int4 c4 = cb4[u];
            const int e0 = u * 4;
            const int cc[4] = {c4.x, c4.y, c4.z, c4.w};
#pragma unroll
            for (int k = 0; k < 4; ++k) {
                const int e = e0 + k;
                const int t = e / cV;
                const int v = e - t * cV;
                if (cc[k] == n && v < slen[t]) slist[atomicAdd(&scount, 1)] = e;
            }
        }
    }

    // pos GEMV: 4 outputs per thread (independent of the scan)
    float4 x = pos_b[tid];
#pragma unroll
    for (int k = 0; k < cAP; ++k) {
        const float4 w = pos_w[k * cD4 + tid];
        const float f = sf[k];
        x.x = fmaf(f, w.x, x.x); x.y = fmaf(f, w.y, x.y);
        x.z = fmaf(f, w.z, x.z); x.w = fmaf(f, w.w, x.w);
    }
    float s  = x.x + x.y + x.z + x.w;
    float ss = x.x * x.x + x.y * x.y + x.z * x.z + x.w * x.w;
    for (int off = 32; off; off >>= 1) {
        s  += __shfl_down(s,  off, 64);
        ss += __shfl_down(ss, off, 64);
    }
    if ((tid & 63) == 0) { red[(tid >> 6) * 2] = s; red[(tid >> 6) * 2 + 1] = ss; }
    __syncthreads();
    if (tid == 0) {
        const float S  = red[0] + red[2] + red[4];
        const float SS = red[1] + red[3] + red[5];
        const float mu  = S / (float)cD;
        const float var = SS / (float)cD - mu * mu;
        red[6] = mu;
        red[7] = rsqrtf(fmaxf(var, 0.f) + cLN_EPS);
    }
    __syncthreads();
    const float mu = red[6], rs = red[7];

    // ---- gather image feature for this node ----
    float ax = 0.f, ay = 0.f, az = 0.f, aw = 0.f;
    float wgt = 0.f;
    if (n > 0) {
        if (tvis >= 0) {
            // visited node: quarter 0 only (helpers + K2 supply quarters 1..3)
            const int len = slen[tvis];
            const int hi  = len >> 2;    // (len*1)/4
            const float4* base = emb + (size_t)(b * cT + tvis) * cV * cD4 + tid;
            int i = 0;
            for (; i + 4 <= hi; i += 4) {
                const float4 a0 = base[(size_t)(i + 0) * cD4];
                const float4 a1 = base[(size_t)(i + 1) * cD4];
                const float4 a2 = base[(size_t)(i + 2) * cD4];
                const float4 a3 = base[(size_t)(i + 3) * cD4];
                ax += (a0.x + a1.x) + (a2.x + a3.x);
                ay += (a0.y + a1.y) + (a2.y + a3.y);
                az += (a0.z + a1.z) + (a2.z + a3.z);
                aw += (a0.w + a1.w) + (a2.w + a3.w);
            }
            for (; i < hi; ++i) {
                const float4 a0 = base[(size_t)i * cD4];
                ax += a0.x; ay += a0.y; az += a0.z; aw += a0.w;
            }
            wgt = 1.0f / (float)len;
        } else {
            __syncthreads();             // scan complete
            const int m = scount;
            if (m > 0) {
                const float4* base = emb + (size_t)b * cTV * cD4 + tid;
                int j = 0;
                for (; j + 4 <= m; j += 4) {
                    const float4 a0 = base[(size_t)slist[j + 0] * cD4];
                    const float4 a1 = base[(size_t)slist[j + 1] * cD4];
                    const float4 a2 = base[(size_t)slist[j + 2] * cD4];
                    const float4 a3 = base[(size_t)slist[j + 3] * cD4];
                    ax += (a0.x + a1.x) + (a2.x + a3.x);
                    ay += (a0.y + a1.y) + (a2.y + a3.y);
                    az += (a0.z + a1.z) + (a2.z + a3.z);
                    aw += (a0.w + a1.w) + (a2.w + a3.w);
                }
                for (; j < m; ++j) {
                    const float4 a0 = base[(size_t)slist[j] * cD4];
                    ax += a0.x; ay += a0.y; az += a0.z; aw += a0.w;
                }
                wgt = 1.0f / (float)m;
            }
        }
    }

    const int sid = step_ids[row];
    const float4 se = step_tab[(size_t)sid * cD4 + tid];
    const float4 g  = ln_g[tid];
    const float4 bb = ln_b[tid];
    float4 o;
    o.x = (x.x - mu) * rs * g.x + bb.x + se.x + ax * wgt;
    o.y = (x.y - mu) * rs * g.y + bb.y + se.y + ay * wgt;
    o.z = (x.z - mu) * rs * g.z + bb.z + se.z + az * wgt;
    o.w = (x.w - mu) * rs * g.w + bb.w + se.w + aw * wgt;
    out[(size_t)row * cD4 + tid] = o;
}

// ---------------------------------------------------------------------------
// K2: add the three helper partials into each visited row.
__global__ __launch_bounds__(192) void k_fix(
    const int*    __restrict__ vp_lens,  // [B,T]
    const int*    __restrict__ vpids,    // [B,T]
    const float4* __restrict__ wsv,      // [B*T*3, D/4]
    float4*       __restrict__ out)      // [B*N, D/4]
{
    const int t = blockIdx.x;            // 0..14
    const int b = blockIdx.y;            // 0..31
    const int node = vpids[b * cT + t];
    if (node <= 0 || node >= cN) return;
    const int len = vp_lens[b * cT + t];
    const int tid = threadIdx.x;
    const size_t sbase = (size_t)((b * cT + t) * 3) * cD4 + tid;
    const float4 p0 = wsv[sbase];
    const float4 p1 = wsv[sbase + cD4];
    const float4 p2 = wsv[sbase + 2 * cD4];
    const float w = 1.0f / (float)len;
    const size_t orow = (size_t)(b * cN + node) * cD4 + tid;
    float4 o = out[orow];
    o.x += ((p0.x + p1.x) + p2.x) * w;
    o.y += ((p0.y + p1.y) + p2.y) * w;
    o.z += ((p0.z + p1.z) + p2.z) * w;
    o.w += ((p0.w + p1.w) + p2.w) * w;
    out[orow] = o;
}

// ---------------------------------------------------------------------------
extern "C" void kernel_launch(void* const* d_in, const int* in_sizes, int n_in,
                              void* d_out, int out_size, void* d_ws, size_t ws_size,
                              hipStream_t stream) {
    const float* emb      = (const float*)d_in[0];   // [B,T,V,D]
    const float* pos_fts  = (const float*)d_in[1];   // [B,N,7]
    const float* step_tab = (const float*)d_in[2];   // [100,D]
    const float* pos_w    = (const float*)d_in[3];   // [7,D]
    const float* pos_b    = (const float*)d_in[4];   // [D]
    const float* ln_g     = (const float*)d_in[5];   // [D]
    const float* ln_b     = (const float*)d_in[6];   // [D]
    const int*   vp_lens  = (const int*)d_in[7];     // [B,T]
    const int*   vpids    = (const int*)d_in[8];     // [B,T]
    const int*   cand     = (const int*)d_in[9];     // [B,T,V]
    const int*   step_ids = (const int*)d_in[10];    // [B,N]
    // d_in[11] = gmap_lens — unused by the reference output

    float4* wsv = (float4*)d_ws;        // 480*3*192 float4 = 4.4 MB

    dim3 g1(cN + cXB, cB);
    k_main<<<g1, 192, 0, stream>>>((const float4*)emb, pos_fts,
                                   (const float4*)step_tab,
                                   (const float4*)pos_w, (const float4*)pos_b,
                                   (const float4*)ln_g, (const float4*)ln_b,
                                   vp_lens, vpids, cand, step_ids,
                                   wsv, (float4*)d_out);
    dim3 g2(cT, cB);
    k_fix<<<g2, 192, 0, stream>>>(vp_lens, vpids, wsv, (float4*)d_out);
}